// Round 22
// baseline (219.835 us; speedup 1.0000x reference)
//
#include <hip/hip_runtime.h>

#define R_ 8
#define N_ 4096
#define D_ 128
#define BM 64
#define KSPLIT 2

typedef __attribute__((ext_vector_type(8))) short bf16x8;
typedef __attribute__((ext_vector_type(4))) float f32x4;

__device__ __forceinline__ unsigned short f2bf(float f) {
  unsigned int u = __builtin_bit_cast(unsigned int, f);
  u += 0x7FFFu + ((u >> 16) & 1u);   // RNE
  return (unsigned short)(u >> 16);
}
// pack 4 f32 -> 4 fp8 e4m3 (OCP) in one dword, RNE
__device__ __forceinline__ unsigned int pk4fp8(float a, float b, float c, float d) {
  int v = __builtin_amdgcn_cvt_pk_fp8_f32(a, b, 0, false);
  v = __builtin_amdgcn_cvt_pk_fp8_f32(c, d, v, true);
  return (unsigned int)v;
}

// async global->LDS, 16 B per lane; LDS dest is wave-uniform base + lane*16
__device__ __forceinline__ void gld16(const void* g, void* l) {
  using GP = const __attribute__((address_space(1))) unsigned int*;
  using LP = __attribute__((address_space(3))) unsigned int*;
  __builtin_amdgcn_global_load_lds((GP)g, (LP)l, 16, 0, 0);
}

// Merged init (R21 verbatim).
__global__ void k_init(const float* __restrict__ emb, const float* __restrict__ rel,
                       unsigned char* __restrict__ embT8a, unsigned short* __restrict__ relb) {
  int b = blockIdx.x;
  if (b < 256) {
    int gt = b * 256 + threadIdx.x;           // 64K units of 8 B
    int C = gt >> 6, l = gt & 63;
    int d = (C & 7) * 16 + (l & 15);
    int k = (C >> 3) * 32 + (l >> 4) * 8;
    float v[8];
#pragma unroll
    for (int i = 0; i < 8; ++i)
      v[i] = emb[(size_t)(k + i) * D_ + d];
    uint2 pk;
    pk.x = pk4fp8(v[0], v[1], v[2], v[3]);
    pk.y = pk4fp8(v[4], v[5], v[6], v[7]);
    *(uint2*)(embT8a + ((size_t)C * 64 + l) * 8) = pk;
  } else {
    int i = (b - 256) * 256 + threadIdx.x;    // over R*D*D
    relb[i] = f2bf(rel[i]);
  }
}

// ---- Layer-1 GEMM: counted-vmcnt pipeline (T4). Double-buffered A in LDS
//      (2x32 KB), B in registers from L2-resident tiled embT8a. Per step:
//      load B(t)->regs, issue A(t+1)->LDS[buf^1], vmcnt(8) [A(t),B(t) done,
//      A(t+1) in flight], barrier, compute, barrier. Loads never drain to 0.
__global__ __launch_bounds__(256, 2) void gcn_gemm1(
    const float* __restrict__ adj,            // [R][N][N] fp32
    const unsigned char* __restrict__ embT8a, // tiled fp8 emb (layer-1 B)
    unsigned char* __restrict__ adjf8,        // [R*64 tiles][256 KB] fp8 tiled
    unsigned short* __restrict__ agg_p)       // [KSPLIT][R][N][D] bf16
{
  __shared__ float As[2][BM * 128];           // 2 x 32 KB: slot s at s^(row&15)

  const int tid  = threadIdx.x;
  const int lane = tid & 63;
  const int w    = tid >> 6;
  const int wr = w >> 1, wc = w & 1;          // 2x2 waves: 32 rows x 64 cols each
  const int fr  = lane & 15;
  const int g   = lane >> 4;                  // 0..3
  const int cr4 = g * 4;

  const int ntile = blockIdx.x;
  const int r     = blockIdx.y;
  const int z     = blockIdx.z;
  const int row0  = ntile * BM;
  const int k0    = z * (N_ / KSPLIT);
  const size_t tbase = (size_t)(r * 64 + ntile) * 262144;   // 256 KB per tile

  const float* gAr = adj + ((size_t)r * N_ + row0) * N_ + k0;

  f32x4 acc[2][4];
#pragma unroll
  for (int m = 0; m < 2; ++m)
#pragma unroll
    for (int n = 0; n < 4; ++n)
      acc[m][n] = (f32x4){0.f, 0.f, 0.f, 0.f};

  // prologue: issue A(0) into buffer 0
#pragma unroll
  for (int i = 0; i < 8; ++i) {
    const int rowbase = w * 16 + i * 2;
    const int ra   = rowbase + (lane >> 5);
    const int slot = (lane & 31) ^ (ra & 15);
    gld16(gAr + (size_t)ra * N_ + slot * 4, &As[0][rowbase * 128]);
  }

  for (int t = 0; t < 16; ++t) {
    // B(t): 16 lane-keyed 8-B loads (coalesced 512 B per wave-load, L2-resident)
    unsigned long long bv[4][4];
#pragma unroll
    for (int kk = 0; kk < 4; ++kk)
#pragma unroll
      for (int n = 0; n < 4; ++n)
        bv[kk][n] = *(const unsigned long long*)
            (embT8a + ((((size_t)(z * 64 + t * 4 + kk) * 8) + wc * 4 + n) * 64 + lane) * 8);

    if (t + 1 < 16) {
      // issue A(t+1) into the other buffer; stays in flight across the barrier
      const int ko = (t + 1) * 128;
#pragma unroll
      for (int i = 0; i < 8; ++i) {
        const int rowbase = w * 16 + i * 2;
        const int ra   = rowbase + (lane >> 5);
        const int slot = (lane & 31) ^ (ra & 15);
        gld16(gAr + (size_t)ra * N_ + ko + slot * 4, &As[(t + 1) & 1][rowbase * 128]);
      }
      asm volatile("s_waitcnt vmcnt(8)" ::: "memory");
    } else {
      asm volatile("s_waitcnt vmcnt(0)" ::: "memory");
    }
    __builtin_amdgcn_sched_barrier(0);
    __builtin_amdgcn_s_barrier();             // all waves: A(t), B(t) resident

    const float* Ab = As[t & 1];
#pragma unroll
    for (int kk = 0; kk < 4; ++kk) {
      unsigned long long av[2];
#pragma unroll
      for (int m = 0; m < 2; ++m) {
        const int row = wr * 32 + m * 16 + fr;
        const int s0  = kk * 8 + g * 2;       // 16-B slot of this lane's k8 (f32)
        f32x4 a0 = *(const f32x4*)&Ab[row * 128 + (((s0    ) ^ (row & 15)) * 4)];
        f32x4 a1 = *(const f32x4*)&Ab[row * 128 + (((s0 + 1) ^ (row & 15)) * 4)];
        unsigned int lo = pk4fp8(a0.x, a0.y, a0.z, a0.w);
        unsigned int hi = pk4fp8(a1.x, a1.y, a1.z, a1.w);
        av[m] = (unsigned long long)lo | ((unsigned long long)hi << 32);
      }
      if (wc == 0) {
        const int G = z * 64 + t * 4 + kk;    // absolute 32-col K-group
        unsigned char* p = adjf8 + tbase + (size_t)(G * 2 + wr) * 1024 + (size_t)lane * 8;
        *(unsigned long long*)p         = av[0];   // m0 fragment (8 fp8)
        *(unsigned long long*)(p + 512) = av[1];   // m1 fragment
      }
#pragma unroll
      for (int n = 0; n < 4; ++n)
#pragma unroll
        for (int m = 0; m < 2; ++m)
          acc[m][n] = __builtin_amdgcn_mfma_f32_16x16x32_fp8_fp8(
              (long)av[m], (long)bv[kk][n], acc[m][n], 0, 0, 0);
    }
    __builtin_amdgcn_s_barrier();             // protect LDS buffer reuse
  }

  unsigned short* gO = agg_p + (((size_t)z * R_ + r) * N_ + row0) * D_;
#pragma unroll
  for (int m = 0; m < 2; ++m)
#pragma unroll
    for (int n = 0; n < 4; ++n)
#pragma unroll
      for (int j = 0; j < 4; ++j) {
        int rl = wr * 32 + m * 16 + cr4 + j;
        int cl = wc * 64 + n * 16 + fr;
        gO[(size_t)rl * D_ + cl] = f2bf(acc[m][n][j]);
      }
}

// ---- Layer-2 GEMM (R21 verbatim): native fp8 MFMA, zero dequant ----
__global__ __launch_bounds__(256, 4) void gcn_gemm2(
    const unsigned char* __restrict__ adjf8,  // tiled fp8 (from gemm1)
    const unsigned char* __restrict__ embT8t, // tiled fp8 emb2 * 2^-16
    unsigned short* __restrict__ agg_p)       // [KSPLIT][R][N][D] bf16, scale 2^-16
{
  __shared__ unsigned char A8[4096];          // [2 G][2 wr][2 m][64 lane][8 B]
  __shared__ unsigned char B8[8192];          // [2 G][8 DB][64 lane][8 B]

  const int tid  = threadIdx.x;
  const int lane = tid & 63;
  const int w    = tid >> 6;                  // wave w: rows w*16 .. w*16+16
  const int fr   = lane & 15;
  const int cr4  = (lane >> 4) * 4;

  const int ntile = blockIdx.x;
  const int r     = blockIdx.y;
  const int z     = blockIdx.z;
  const int row0  = ntile * BM;
  const size_t tbase = (size_t)(r * 64 + ntile) * 262144;

  f32x4 acc[8];
#pragma unroll
  for (int n = 0; n < 8; ++n)
    acc[n] = (f32x4){0.f, 0.f, 0.f, 0.f};

  for (int t = 0; t < 32; ++t) {              // BK=64 steps
    const int G0 = z * 64 + t * 2;            // two 32-k groups per step
    gld16(adjf8 + tbase + (size_t)G0 * 2048 + (size_t)w * 1024 + (size_t)lane * 16,
          A8 + w * 1024);
#pragma unroll
    for (int i = 0; i < 2; ++i) {
      const int c = i * 4 + w;
      gld16(embT8t + (size_t)G0 * 4096 + (size_t)c * 1024 + (size_t)lane * 16,
            B8 + c * 1024);
    }
    __syncthreads();

#pragma unroll
    for (int kk = 0; kk < 2; ++kk) {
      const long av = *(const long*)&A8[(((kk * 2 + (w >> 1)) * 2 + (w & 1)) * 64 + lane) * 8];
#pragma unroll
      for (int n = 0; n < 8; ++n) {
        const long bv = *(const long*)&B8[((kk * 8 + n) * 64 + lane) * 8];
        acc[n] = __builtin_amdgcn_mfma_f32_16x16x32_fp8_fp8(av, bv, acc[n], 0, 0, 0);
      }
    }
    __syncthreads();
  }

  unsigned short* gO = agg_p + (((size_t)z * R_ + r) * N_ + row0) * D_;
#pragma unroll
  for (int n = 0; n < 8; ++n)
#pragma unroll
    for (int j = 0; j < 4; ++j) {
      int rl = w * 16 + cr4 + j;
      int cl = n * 16 + fr;
      gO[(size_t)rl * D_ + cl] = f2bf(acc[n][j]);
    }
}

// Pass 2 (R21 verbatim): tmp = agg_p @ rel^T summed over z,r.
__global__ __launch_bounds__(256) void gcn_pass2(
    const unsigned short* __restrict__ agg_p,  // [KSPLIT][R][N][D] bf16
    const unsigned short* __restrict__ relb,   // [R][D][D] bf16
    float* __restrict__ out,                   // [N][D] f32
    unsigned char* __restrict__ embT8t,        // tiled fp8 (layer-2 B)
    int write_out, int write_embT)
{
  const int tid  = threadIdx.x;
  const int lane = tid & 63;
  const int w    = tid >> 6;
  const int n0   = blockIdx.x * 16;
  const int col0 = w * 32;
  const int fr   = lane & 15;
  const int e8   = (lane >> 4) * 8;
  const int cr4  = (lane >> 4) * 4;

  f32x4 tacc[2];
  tacc[0] = (f32x4){0.f, 0.f, 0.f, 0.f};
  tacc[1] = (f32x4){0.f, 0.f, 0.f, 0.f};

  for (int r = 0; r < R_; ++r) {
    bf16x8 a[2][4], b[2][4];
#pragma unroll
    for (int zz = 0; zz < 2; ++zz)
#pragma unroll
      for (int kk = 0; kk < 4; ++kk)
        a[zz][kk] = *(const bf16x8*)&agg_p[(((size_t)zz * R_ + r) * N_ + n0 + fr) * D_ + kk * 32 + e8];
#pragma unroll
    for (int n = 0; n < 2; ++n)
#pragma unroll
      for (int kk = 0; kk < 4; ++kk)
        b[n][kk] = *(const bf16x8*)&relb[(size_t)r * D_ * D_ + (col0 + n * 16 + fr) * D_ + kk * 32 + e8];
#pragma unroll
    for (int n = 0; n < 2; ++n)
#pragma unroll
      for (int kk = 0; kk < 4; ++kk)
#pragma unroll
        for (int zz = 0; zz < 2; ++zz)
          tacc[n] = __builtin_amdgcn_mfma_f32_16x16x32_bf16(a[zz][kk], b[n][kk], tacc[n], 0, 0, 0);
  }

#pragma unroll
  for (int n = 0; n < 2; ++n) {
    if (write_out) {
#pragma unroll
      for (int j = 0; j < 4; ++j) {
        int row = n0 + cr4 + j;
        int col = col0 + n * 16 + fr;
        float v = tacc[n][j] * 8192.f;        // 0.125 mean * 2^16 fp8-scale undo
        out[(size_t)row * D_ + col] = v > 0.f ? v : 0.f;
      }
    }
    if (write_embT) {
      const float s = 0.125f * 1.52587890625e-05f;   // mean * 2^-16 range scale
      float v[4];
#pragma unroll
      for (int j = 0; j < 4; ++j) {
        float x = tacc[n][j];
        v[j] = (x > 0.f ? x : 0.f) * s;
      }
      unsigned int pk = pk4fp8(v[0], v[1], v[2], v[3]);
      const int G   = n0 >> 5;
      const int gfr = ((n0 & 31) + cr4) >> 3;
      const int h   = (cr4 >> 2) & 1;
      const int DB  = w * 2 + n;
      *(unsigned int*)(embT8t + (size_t)(G * 8 + DB) * 512 + (fr + gfr * 16) * 8 + h * 4) = pk;
    }
  }
}

extern "C" void kernel_launch(void* const* d_in, const int* in_sizes, int n_in,
                              void* d_out, int out_size, void* d_ws, size_t ws_size,
                              hipStream_t stream) {
  const float* adj = (const float*)d_in[0];   // [R][N][N]
  const float* emb = (const float*)d_in[1];   // [N][D]
  const float* rel = (const float*)d_in[2];   // [R][D][D]
  float* out = (float*)d_out;                 // [N][D] f32

  unsigned short* relb   = (unsigned short*)d_ws;                // 256 KB
  unsigned short* agg_p  = relb + (size_t)R_ * D_ * D_;          // 16 MB
  unsigned char*  embT8a = (unsigned char*)(agg_p + (size_t)2 * R_ * N_ * D_);  // 512 KB (L1 B)
  unsigned char*  embT8t = embT8a + (size_t)512 * 1024;          // 512 KB (L2 B)
  unsigned char*  adjf8  = embT8t + (size_t)512 * 1024;          // 128 MB

  k_init<<<768, 256, 0, stream>>>(emb, rel, embT8a, relb);

  dim3 grid(N_ / BM, R_, KSPLIT);
  gcn_gemm1<<<grid, 256, 0, stream>>>(adj, embT8a, adjf8, agg_p);
  gcn_pass2<<<N_ / 16, 256, 0, stream>>>(agg_p, relb, out, embT8t, /*write_out=*/0, /*write_embT=*/1);
  gcn_gemm2<<<grid, 256, 0, stream>>>(adjf8, embT8t, agg_p);
  gcn_pass2<<<N_ / 16, 256, 0, stream>>>(agg_p, relb, out, embT8t, /*write_out=*/1, /*write_embT=*/0);
}

// Round 23
// 216.248 us; speedup vs baseline: 1.0166x; 1.0166x over previous
//
#include <hip/hip_runtime.h>

#define R_ 8
#define N_ 4096
#define D_ 128
#define BM 64
#define KSPLIT 2

typedef __attribute__((ext_vector_type(8))) short bf16x8;
typedef __attribute__((ext_vector_type(4))) float f32x4;

__device__ __forceinline__ unsigned short f2bf(float f) {
  unsigned int u = __builtin_bit_cast(unsigned int, f);
  u += 0x7FFFu + ((u >> 16) & 1u);   // RNE
  return (unsigned short)(u >> 16);
}
// pack 4 f32 -> 4 fp8 e4m3 (OCP) in one dword, RNE
__device__ __forceinline__ unsigned int pk4fp8(float a, float b, float c, float d) {
  int v = __builtin_amdgcn_cvt_pk_fp8_f32(a, b, 0, false);
  v = __builtin_amdgcn_cvt_pk_fp8_f32(c, d, v, true);
  return (unsigned int)v;
}

// async global->LDS, 16 B per lane; LDS dest is wave-uniform base + lane*16
__device__ __forceinline__ void gld16(const void* g, void* l) {
  using GP = const __attribute__((address_space(1))) unsigned int*;
  using LP = __attribute__((address_space(3))) unsigned int*;
  __builtin_amdgcn_global_load_lds((GP)g, (LP)l, 16, 0, 0);
}

// Merged init (R21 verbatim).
__global__ void k_init(const float* __restrict__ emb, const float* __restrict__ rel,
                       unsigned char* __restrict__ embT8a, unsigned short* __restrict__ relb) {
  int b = blockIdx.x;
  if (b < 256) {
    int gt = b * 256 + threadIdx.x;           // 64K units of 8 B
    int C = gt >> 6, l = gt & 63;
    int d = (C & 7) * 16 + (l & 15);
    int k = (C >> 3) * 32 + (l >> 4) * 8;
    float v[8];
#pragma unroll
    for (int i = 0; i < 8; ++i)
      v[i] = emb[(size_t)(k + i) * D_ + d];
    uint2 pk;
    pk.x = pk4fp8(v[0], v[1], v[2], v[3]);
    pk.y = pk4fp8(v[4], v[5], v[6], v[7]);
    *(uint2*)(embT8a + ((size_t)C * 64 + l) * 8) = pk;
  } else {
    int i = (b - 256) * 256 + threadIdx.x;    // over R*D*D
    relb[i] = f2bf(rel[i]);
  }
}

// ---- Layer-1 GEMM (R21 verbatim): fp32 adj, fp8 MFMA, fused fp8 copy ----
__global__ __launch_bounds__(256, 3) void gcn_gemm1(
    const float* __restrict__ adj,            // [R][N][N] fp32
    const unsigned char* __restrict__ embT8a, // tiled fp8 emb (layer-1 B)
    unsigned char* __restrict__ adjf8,        // [R*64 tiles][256 KB] fp8 tiled
    unsigned short* __restrict__ agg_p)       // [KSPLIT][R][N][D] bf16
{
  __shared__ float         As[BM * 128];      // 32 KB: slot s stored at s^(row&15)
  __shared__ unsigned char B8[16384];         // 16 KB: [4 G][8 DB][64 lane][8 B]

  const int tid  = threadIdx.x;
  const int lane = tid & 63;
  const int w    = tid >> 6;
  const int wr = w >> 1, wc = w & 1;          // 2x2 waves: 32 rows x 64 cols each
  const int fr  = lane & 15;
  const int g   = lane >> 4;                  // 0..3
  const int cr4 = g * 4;

  const int ntile = blockIdx.x;
  const int r     = blockIdx.y;
  const int z     = blockIdx.z;
  const int row0  = ntile * BM;
  const int k0    = z * (N_ / KSPLIT);
  const size_t tbase = (size_t)(r * 64 + ntile) * 262144;   // 256 KB per tile

  const float* gAr = adj + ((size_t)r * N_ + row0) * N_ + k0;

  f32x4 acc[2][4];
#pragma unroll
  for (int m = 0; m < 2; ++m)
#pragma unroll
    for (int n = 0; n < 4; ++n)
      acc[m][n] = (f32x4){0.f, 0.f, 0.f, 0.f};

  for (int t = 0; t < 16; ++t) {              // NSTEP = 2048/128
    const int ko = t * 128;
    // A: 8 instrs/wave, each 1 KB = 2 rows x 512 B (32 slots); source pre-swizzled
#pragma unroll
    for (int i = 0; i < 8; ++i) {
      const int rowbase = w * 16 + i * 2;
      const int ra   = rowbase + (lane >> 5);
      const int slot = (lane & 31) ^ (ra & 15);
      gld16(gAr + (size_t)ra * N_ + ko + slot * 4, As + rowbase * 128);
    }
    // B: 4 instrs/wave, 16 KB total, pure sequential from tiled embT8a
    {
      const unsigned char* src = embT8a + (size_t)(z * 64 + t * 4) * 4096;
#pragma unroll
      for (int i = 0; i < 4; ++i) {
        const int c = i * 4 + w;
        gld16(src + (size_t)c * 1024 + (size_t)lane * 16, B8 + c * 1024);
      }
    }
    __syncthreads();                          // drain DMA -> tile resident

#pragma unroll
    for (int kk = 0; kk < 4; ++kk) {
      unsigned long long av[2];
#pragma unroll
      for (int m = 0; m < 2; ++m) {
        const int row = wr * 32 + m * 16 + fr;
        const int s0  = kk * 8 + g * 2;       // 16-B slot of this lane's k8 (f32)
        f32x4 a0 = *(const f32x4*)&As[row * 128 + (((s0    ) ^ (row & 15)) * 4)];
        f32x4 a1 = *(const f32x4*)&As[row * 128 + (((s0 + 1) ^ (row & 15)) * 4)];
        unsigned int lo = pk4fp8(a0.x, a0.y, a0.z, a0.w);
        unsigned int hi = pk4fp8(a1.x, a1.y, a1.z, a1.w);
        av[m] = (unsigned long long)lo | ((unsigned long long)hi << 32);
      }
      if (wc == 0) {
        const int G = z * 64 + t * 4 + kk;    // absolute 32-col K-group
        unsigned char* p = adjf8 + tbase + (size_t)(G * 2 + wr) * 1024 + (size_t)lane * 8;
        *(unsigned long long*)p         = av[0];   // m0 fragment (8 fp8)
        *(unsigned long long*)(p + 512) = av[1];   // m1 fragment
      }
#pragma unroll
      for (int n = 0; n < 4; ++n) {
        const int DB = wc * 4 + n;
        const long bv = *(const long*)&B8[((kk * 8 + DB) * 64 + lane) * 8];
#pragma unroll
        for (int m = 0; m < 2; ++m)
          acc[m][n] = __builtin_amdgcn_mfma_f32_16x16x32_fp8_fp8((long)av[m], bv, acc[m][n], 0, 0, 0);
      }
    }
    __syncthreads();                          // protect LDS overwrite next step
  }

  unsigned short* gO = agg_p + (((size_t)z * R_ + r) * N_ + row0) * D_;
#pragma unroll
  for (int m = 0; m < 2; ++m)
#pragma unroll
    for (int n = 0; n < 4; ++n)
#pragma unroll
      for (int j = 0; j < 4; ++j) {
        int rl = wr * 32 + m * 16 + cr4 + j;
        int cl = wc * 64 + n * 16 + fr;
        gO[(size_t)rl * D_ + cl] = f2bf(acc[m][n][j]);
      }
}

// ---- Layer-2 GEMM (R21 verbatim): native fp8 MFMA, zero dequant ----
__global__ __launch_bounds__(256, 4) void gcn_gemm2(
    const unsigned char* __restrict__ adjf8,  // tiled fp8 (from gemm1)
    const unsigned char* __restrict__ embT8t, // tiled fp8 emb2 * 2^-16
    unsigned short* __restrict__ agg_p)       // [KSPLIT][R][N][D] bf16, scale 2^-16
{
  __shared__ unsigned char A8[4096];          // [2 G][2 wr][2 m][64 lane][8 B]
  __shared__ unsigned char B8[8192];          // [2 G][8 DB][64 lane][8 B]

  const int tid  = threadIdx.x;
  const int lane = tid & 63;
  const int w    = tid >> 6;                  // wave w: rows w*16 .. w*16+16
  const int fr   = lane & 15;
  const int cr4  = (lane >> 4) * 4;

  const int ntile = blockIdx.x;
  const int r     = blockIdx.y;
  const int z     = blockIdx.z;
  const int row0  = ntile * BM;
  const size_t tbase = (size_t)(r * 64 + ntile) * 262144;

  f32x4 acc[8];
#pragma unroll
  for (int n = 0; n < 8; ++n)
    acc[n] = (f32x4){0.f, 0.f, 0.f, 0.f};

  for (int t = 0; t < 32; ++t) {              // BK=64 steps
    const int G0 = z * 64 + t * 2;            // two 32-k groups per step
    gld16(adjf8 + tbase + (size_t)G0 * 2048 + (size_t)w * 1024 + (size_t)lane * 16,
          A8 + w * 1024);
#pragma unroll
    for (int i = 0; i < 2; ++i) {
      const int c = i * 4 + w;
      gld16(embT8t + (size_t)G0 * 4096 + (size_t)c * 1024 + (size_t)lane * 16,
            B8 + c * 1024);
    }
    __syncthreads();

#pragma unroll
    for (int kk = 0; kk < 2; ++kk) {
      const long av = *(const long*)&A8[(((kk * 2 + (w >> 1)) * 2 + (w & 1)) * 64 + lane) * 8];
#pragma unroll
      for (int n = 0; n < 8; ++n) {
        const long bv = *(const long*)&B8[((kk * 8 + n) * 64 + lane) * 8];
        acc[n] = __builtin_amdgcn_mfma_f32_16x16x32_fp8_fp8(av, bv, acc[n], 0, 0, 0);
      }
    }
    __syncthreads();
  }

  unsigned short* gO = agg_p + (((size_t)z * R_ + r) * N_ + row0) * D_;
#pragma unroll
  for (int n = 0; n < 8; ++n)
#pragma unroll
    for (int j = 0; j < 4; ++j) {
      int rl = w * 16 + cr4 + j;
      int cl = n * 16 + fr;
      gO[(size_t)rl * D_ + cl] = f2bf(acc[n][j]);
    }
}

// Pass 2: tmp = agg_p @ rel^T summed over z,r; software-pipelined over r
// (1 wave/SIMD at this grid -> no TLP; ILP via double-buffered operand regs).
// MFMA order identical to R21 -> bit-identical output.
__global__ __launch_bounds__(256) void gcn_pass2(
    const unsigned short* __restrict__ agg_p,  // [KSPLIT][R][N][D] bf16
    const unsigned short* __restrict__ relb,   // [R][D][D] bf16
    float* __restrict__ out,                   // [N][D] f32
    unsigned char* __restrict__ embT8t,        // tiled fp8 (layer-2 B)
    int write_out, int write_embT)
{
  const int tid  = threadIdx.x;
  const int lane = tid & 63;
  const int w    = tid >> 6;
  const int n0   = blockIdx.x * 16;
  const int col0 = w * 32;
  const int fr   = lane & 15;
  const int e8   = (lane >> 4) * 8;
  const int cr4  = (lane >> 4) * 4;

  f32x4 tacc[2];
  tacc[0] = (f32x4){0.f, 0.f, 0.f, 0.f};
  tacc[1] = (f32x4){0.f, 0.f, 0.f, 0.f};

  bf16x8 aA[2][4], bA[2][4], aB[2][4], bB[2][4];   // double-buffered operands

#define P2_LOAD(rr, AA, BB)                                                        \
  {                                                                                \
    _Pragma("unroll")                                                              \
    for (int zz = 0; zz < 2; ++zz)                                                 \
      _Pragma("unroll")                                                            \
      for (int kk = 0; kk < 4; ++kk)                                               \
        AA[zz][kk] = *(const bf16x8*)&agg_p[(((size_t)zz * R_ + (rr)) * N_ + n0 + fr) * D_ + kk * 32 + e8]; \
    _Pragma("unroll")                                                              \
    for (int n = 0; n < 2; ++n)                                                    \
      _Pragma("unroll")                                                            \
      for (int kk = 0; kk < 4; ++kk)                                               \
        BB[n][kk] = *(const bf16x8*)&relb[(size_t)(rr) * D_ * D_ + (col0 + n * 16 + fr) * D_ + kk * 32 + e8]; \
  }

#define P2_COMP(AA, BB)                                                            \
  {                                                                                \
    _Pragma("unroll")                                                              \
    for (int n = 0; n < 2; ++n)                                                    \
      _Pragma("unroll")                                                            \
      for (int kk = 0; kk < 4; ++kk)                                               \
        _Pragma("unroll")                                                          \
        for (int zz = 0; zz < 2; ++zz)                                             \
          tacc[n] = __builtin_amdgcn_mfma_f32_16x16x32_bf16(AA[zz][kk], BB[n][kk], tacc[n], 0, 0, 0); \
  }

  P2_LOAD(0, aA, bA)
  P2_LOAD(1, aB, bB)
  P2_COMP(aA, bA)
  P2_LOAD(2, aA, bA)
  P2_COMP(aB, bB)
  P2_LOAD(3, aB, bB)
  P2_COMP(aA, bA)
  P2_LOAD(4, aA, bA)
  P2_COMP(aB, bB)
  P2_LOAD(5, aB, bB)
  P2_COMP(aA, bA)
  P2_LOAD(6, aA, bA)
  P2_COMP(aB, bB)
  P2_LOAD(7, aB, bB)
  P2_COMP(aA, bA)
  P2_COMP(aB, bB)
#undef P2_LOAD
#undef P2_COMP

#pragma unroll
  for (int n = 0; n < 2; ++n) {
    if (write_out) {
#pragma unroll
      for (int j = 0; j < 4; ++j) {
        int row = n0 + cr4 + j;
        int col = col0 + n * 16 + fr;
        float v = tacc[n][j] * 8192.f;        // 0.125 mean * 2^16 fp8-scale undo
        out[(size_t)row * D_ + col] = v > 0.f ? v : 0.f;
      }
    }
    if (write_embT) {
      const float s = 0.125f * 1.52587890625e-05f;   // mean * 2^-16 range scale
      float v[4];
#pragma unroll
      for (int j = 0; j < 4; ++j) {
        float x = tacc[n][j];
        v[j] = (x > 0.f ? x : 0.f) * s;
      }
      unsigned int pk = pk4fp8(v[0], v[1], v[2], v[3]);
      const int G   = n0 >> 5;
      const int gfr = ((n0 & 31) + cr4) >> 3;
      const int h   = (cr4 >> 2) & 1;
      const int DB  = w * 2 + n;
      *(unsigned int*)(embT8t + (size_t)(G * 8 + DB) * 512 + (fr + gfr * 16) * 8 + h * 4) = pk;
    }
  }
}

extern "C" void kernel_launch(void* const* d_in, const int* in_sizes, int n_in,
                              void* d_out, int out_size, void* d_ws, size_t ws_size,
                              hipStream_t stream) {
  const float* adj = (const float*)d_in[0];   // [R][N][N]
  const float* emb = (const float*)d_in[1];   // [N][D]
  const float* rel = (const float*)d_in[2];   // [R][D][D]
  float* out = (float*)d_out;                 // [N][D] f32

  unsigned short* relb   = (unsigned short*)d_ws;                // 256 KB
  unsigned short* agg_p  = relb + (size_t)R_ * D_ * D_;          // 16 MB
  unsigned char*  embT8a = (unsigned char*)(agg_p + (size_t)2 * R_ * N_ * D_);  // 512 KB (L1 B)
  unsigned char*  embT8t = embT8a + (size_t)512 * 1024;          // 512 KB (L2 B)
  unsigned char*  adjf8  = embT8t + (size_t)512 * 1024;          // 128 MB

  k_init<<<768, 256, 0, stream>>>(emb, rel, embT8a, relb);

  dim3 grid(N_ / BM, R_, KSPLIT);
  gcn_gemm1<<<grid, 256, 0, stream>>>(adj, embT8a, adjf8, agg_p);
  gcn_pass2<<<N_ / 16, 256, 0, stream>>>(agg_p, relb, out, embT8t, /*write_out=*/0, /*write_embT=*/1);
  gcn_gemm2<<<grid, 256, 0, stream>>>(adjf8, embT8t, agg_p);
  gcn_pass2<<<N_ / 16, 256, 0, stream>>>(agg_p, relb, out, embT8t, /*write_out=*/1, /*write_embT=*/0);
}